// Round 6
// baseline (41.032 us; speedup 1.0000x reference)
//
#include <hip/hip_runtime.h>
#include <math.h>

// EigenMatrixGenerator: N=40 grid, state S=4800.
// Analytic collapse: A = Re(P diag(L) P^H), P diagonal-block structured =>
//   A[0,0](i) = lam1 + 2*Re(lam2)                        (= d1)
//   A[1,1]=A[1,2]=A[2,1]=A[2,2](i) = 2*|v2|^2*Re(lam2)   (= d2)
//   all other blocks Re(z - conj(z)) = 0.
// W = (A - 0.97 I)/0.03. Outputs: A, W (23.04M f32), c_pos, k (1600 each).
//
// Pure HBM-write-bound (184.3 MB irreducible). R6 = R3's flat grid-stride
// classify-and-store with NON-TEMPORAL stores (nt) via ext_vector_type
// (HIP_vector_type float4* is rejected by the builtin). No barriers
// (R4 lesson: __syncthreads => vmcnt(0) drain mid-stream costs ~4 us).

typedef float f32x4 __attribute__((ext_vector_type(4)));

constexpr int       GN   = 40;
constexpr int       G    = GN * GN;              // 1600
constexpr int       S    = 3 * G;                // 4800
constexpr long long SS   = (long long)S * S;     // 23,040,000
constexpr unsigned  ROW4 = S / 4;                // 1200 float4 per row
constexpr unsigned  SS4  = (unsigned)(SS / 4);   // 5,760,000 float4 per matrix
constexpr unsigned  TOT4 = 2 * SS4 + (2 * G) / 4;  // 11,520,800 total float4

__device__ __forceinline__ float softplus_f(float x) {
    return fmaxf(x, 0.0f) + log1pf(expf(-fabsf(x)));
}

__global__ __launch_bounds__(256) void eigen_flat_nt_kernel(
        const float* __restrict__ c,
        const float* __restrict__ k,
        const float* __restrict__ kp,
        float* __restrict__ out) {
    unsigned i      = blockIdx.x * 256u + threadIdx.x;
    unsigned stride = gridDim.x * 256u;
    f32x4* __restrict__ out4 = (f32x4*)out;

    for (; i < TOT4; i += stride) {
        if (i >= 2 * SS4) {
            // tail: c_pos (1600 floats) then k passthrough (1600 floats)
            unsigned base = (i - 2 * SS4) * 4;
            f32x4 v;
#pragma unroll
            for (int j = 0; j < 4; ++j) {
                unsigned idx = base + j;
                v[j] = (idx < (unsigned)G) ? softplus_f(c[idx]) : k[idx - G];
            }
            __builtin_nontemporal_store(v, out4 + i);
            continue;
        }

        bool     isW = i >= SS4;
        unsigned fr  = isW ? i - SS4 : i;        // float4 index within matrix
        unsigned r   = fr / ROW4;                // row 0..4799 (magic mul)
        unsigned i4  = fr - r * ROW4;            // float4-col 0..1199
        unsigned b   = r / (unsigned)G;          // block-row 0..2
        unsigned g   = r - b * (unsigned)G;      // grid index

        unsigned q1, q2;
        if (b == 0) { q1 = g >> 2;                   q2 = 0xffffffffu; }
        else        { q1 = ((unsigned)G + g) >> 2;   q2 = (2u * G + g) >> 2; }

        f32x4 v = (f32x4)(0.0f);

        if (i4 == q1 || i4 == q2) {              // rare: 16000 / 11.5M float4s
            float c_pos = softplus_f(c[g]);
            float k_x   = softplus_f(k[g]);
            float kp_p  = softplus_f(kp[g]);

            const float xi = 1.57079632679489662f;   // float32(pi/2), DT=1
            float okx  = 1.0f + k_x;
            float okp  = 1.0f + kp_p;
            float lam1 = 1.0f / okx;
            float rp   = 0.5f * (1.0f / okp + lam1);     // Re(lam2)
            float im   = c_pos * xi / sqrtf(okp * okx);  // Im(lam2)
            float ar   = rp - lam1 + 1e-6f;
            float bx   = lam1 * xi;
            float v2sq = bx * bx / (ar * ar + im * im);

            float d1 = lam1 + 2.0f * rp;
            float d2 = 2.0f * v2sq * rp;

            const float INV_L = 1.0f / 0.03f;
            const float OML   = 0.97f;

            unsigned c1, c2;
            float    v1, v2v;
            if (b == 0) {
                c1 = g;                 v1  = isW ? (d1 - OML) * INV_L : d1;
                c2 = 0xffffffffu;       v2v = 0.0f;
            } else if (b == 1) {
                c1 = (unsigned)G + g;   v1  = isW ? (d2 - OML) * INV_L : d2;  // diag
                c2 = 2u * G + g;        v2v = isW ? d2 * INV_L : d2;          // off
            } else {
                c1 = (unsigned)G + g;   v1  = isW ? d2 * INV_L : d2;          // off
                c2 = 2u * G + g;        v2v = isW ? (d2 - OML) * INV_L : d2;  // diag
            }

            unsigned c0 = i4 * 4;
#pragma unroll
            for (int j = 0; j < 4; ++j) {
                unsigned col = c0 + j;
                if (col == c1)      v[j] = v1;
                else if (col == c2) v[j] = v2v;
            }
        }

        __builtin_nontemporal_store(v, out4 + i);
    }
}

extern "C" void kernel_launch(void* const* d_in, const int* in_sizes, int n_in,
                              void* d_out, int out_size, void* d_ws, size_t ws_size,
                              hipStream_t stream) {
    const float* c  = (const float*)d_in[0];
    const float* k  = (const float*)d_in[1];
    const float* kp = (const float*)d_in[2];
    float* out = (float*)d_out;

    eigen_flat_nt_kernel<<<2048, 256, 0, stream>>>(c, k, kp, out);
}

// Round 7
// 32.575 us; speedup vs baseline: 1.2596x; 1.2596x over previous
//
#include <hip/hip_runtime.h>
#include <math.h>

// EigenMatrixGenerator: N=40 grid, state S=4800.
// Analytic collapse: A = Re(P diag(L) P^H) with P made of diagonal blocks
//   [I I I; 0 D(v2) D(v3); 0 D(v2) D(v3)], v3 = -conj(v2), lam3 = conj(lam2).
// => A[0,1]=A[0,2]=A[1,0]=A[2,0]=0 blocks (z - conj(z) is purely imaginary)
//    A[0,0](i)                       = lam1 + 2*real_part            (= d1)
//    A[1,1]=A[1,2]=A[2,1]=A[2,2](i)  = 2*|v2|^2*real_part            (= d2)
// W = (A - 0.97 I)/0.03.
// Outputs: A (23.04M f32), W (23.04M), c_pos (1600), k (1600) = 184.3 MB.
//
// Pure HBM-write-bound; best measured variant (R2, 32.88 us): one block per
// row, coalesced float4 streaming with <=2 nonzeros patched inline.
// Lessons encoded: no __syncthreads mid-stream (R4: +4us vmcnt(0) drain);
// no nontemporal stores (R6: +8us, L2 write-combining helps streaming).

constexpr int       GN = 40;
constexpr int       G  = GN * GN;        // 1600
constexpr int       S  = 3 * G;          // 4800
constexpr long long SS = (long long)S * S;  // 23,040,000
constexpr int       ROW4 = S / 4;        // 1200 float4 per row

__device__ __forceinline__ float softplus_f(float x) {
    // jax.nn.softplus = max(x,0) + log1p(exp(-|x|))
    return fmaxf(x, 0.0f) + log1pf(expf(-fabsf(x)));
}

__global__ __launch_bounds__(256) void eigen_rows_kernel(
        const float* __restrict__ c,
        const float* __restrict__ k,
        const float* __restrict__ kp,
        float* __restrict__ out) {
    int r = blockIdx.x;                  // 0..9599 = rows of [A; W], 9600 = tail

    if (r >= 2 * S) {
        // tail: c_pos (40x40) then k passthrough (40x40)
        for (int i = threadIdx.x; i < G; i += 256) {
            out[2 * SS + i]     = softplus_f(c[i]);
            out[2 * SS + G + i] = k[i];
        }
        return;
    }

    bool isW = r >= S;
    int  rr  = isW ? r - S : r;          // row within the 4800x4800 matrix
    int  b   = rr / G;                   // block row 0,1,2 (wave-uniform)
    int  g   = rr % G;                   // grid index

    // per-index eigen values (wave-uniform scalar math; inputs L2-resident)
    float c_pos = softplus_f(c[g]);
    float k_x   = softplus_f(k[g]);
    float kp_p  = softplus_f(kp[g]);

    const float xi = 1.57079632679489662f;   // float32(pi/2), DT = 1
    float okx  = 1.0f + k_x;
    float okp  = 1.0f + kp_p;
    float lam1 = 1.0f / okx;
    float rp   = 0.5f * (1.0f / okp + lam1);     // Re(lam2)
    float im   = c_pos * xi / sqrtf(okp * okx);  // Im(lam2)
    float ar   = rp - lam1 + 1e-6f;              // Re(alpha)
    float bx   = lam1 * xi;                      // beta*xi (beta = lam1)
    float v2sq = bx * bx / (ar * ar + im * im);  // |v2|^2

    float d1 = lam1 + 2.0f * rp;                 // A[0,0] diag
    float d2 = 2.0f * v2sq * rp;                 // A[1,1]=A[1,2]=A[2,1]=A[2,2]

    const float INV_L = 1.0f / 0.03f;
    const float OML   = 0.97f;

    // nonzero columns c1 <= c2 and their values for this row
    int   c1, c2;
    float v1, v2v;
    if (b == 0) {
        c1 = g;      v1 = isW ? (d1 - OML) * INV_L : d1;
        c2 = -1;     v2v = 0.0f;
    } else if (b == 1) {
        c1 = G + g;      v1  = isW ? (d2 - OML) * INV_L : d2;   // diagonal
        c2 = 2 * G + g;  v2v = isW ? d2 * INV_L : d2;           // off-diag
    } else {
        c1 = G + g;      v1  = isW ? d2 * INV_L : d2;           // off-diag
        c2 = 2 * G + g;  v2v = isW ? (d2 - OML) * INV_L : d2;   // diagonal
    }

    float4* __restrict__ row4 = (float4*)out + (long long)r * ROW4;
    for (int i4 = threadIdx.x; i4 < ROW4; i4 += 256) {
        int c0 = i4 * 4;
        float4 v;
        v.x = (c0     == c1) ? v1 : ((c0     == c2) ? v2v : 0.0f);
        v.y = (c0 + 1 == c1) ? v1 : ((c0 + 1 == c2) ? v2v : 0.0f);
        v.z = (c0 + 2 == c1) ? v1 : ((c0 + 2 == c2) ? v2v : 0.0f);
        v.w = (c0 + 3 == c1) ? v1 : ((c0 + 3 == c2) ? v2v : 0.0f);
        row4[i4] = v;
    }
}

extern "C" void kernel_launch(void* const* d_in, const int* in_sizes, int n_in,
                              void* d_out, int out_size, void* d_ws, size_t ws_size,
                              hipStream_t stream) {
    const float* c  = (const float*)d_in[0];
    const float* k  = (const float*)d_in[1];
    const float* kp = (const float*)d_in[2];
    float* out = (float*)d_out;

    eigen_rows_kernel<<<2 * S + 1, 256, 0, stream>>>(c, k, kp, out);
}